// Round 4
// baseline (541.898 us; speedup 1.0000x reference)
//
#include <hip/hip_runtime.h>

#define BB   4
#define SS   2048
#define HH   16
#define DM   1024
#define DKV  64
#define LNEPS 1e-6f

#define MD_BF16 0
#define MD_F32  1
#define MD_F16  2

typedef __attribute__((ext_vector_type(8))) short bf16x8;
typedef __attribute__((ext_vector_type(4))) float f32x4;
#define MFMA16(a,b,c) __builtin_amdgcn_mfma_f32_16x16x32_bf16(a,b,c,0,0,0)

// async global->LDS DMA, 16B per lane (dest = wave-uniform base + lane*16)
__device__ __forceinline__ void gl_lds16(const ushort* g, ushort* l) {
    __builtin_amdgcn_global_load_lds(
        (const __attribute__((address_space(1))) void*)g,
        (__attribute__((address_space(3))) void*)l, 16, 0, 0);
}
__device__ __forceinline__ void wait_vm0_barrier() {
    asm volatile("s_waitcnt vmcnt(0)" ::: "memory");
    __builtin_amdgcn_s_barrier();
}

// ---------- dtype helpers ----------
__device__ __forceinline__ float2 unpack2(unsigned int u) {
    union { unsigned int i; float f; } a, b;
    a.i = u << 16;
    b.i = u & 0xffff0000u;
    return make_float2(a.f, b.f);
}
__device__ __forceinline__ unsigned short f2bf(float f) {   // RNE
    union { float f; unsigned int i; } c; c.f = f;
    unsigned int u = c.i;
    unsigned int r = u + 0x7fffu + ((u >> 16) & 1u);
    return (unsigned short)(r >> 16);
}
__device__ __forceinline__ unsigned short f2bf_t(float f) { // truncate
    union { float f; unsigned int i; } c; c.f = f;
    return (unsigned short)(c.i >> 16);
}
__device__ __forceinline__ float h2f(unsigned int bits16) {
    unsigned short s = (unsigned short)bits16;
    _Float16 x;
    __builtin_memcpy(&x, &s, 2);
    return (float)x;
}
__device__ __forceinline__ void load4m(const void* p, int mode, size_t e0, float* o) {
    if (mode == MD_F32) {
        float4 v = *(const float4*)((const float*)p + e0);
        o[0] = v.x; o[1] = v.y; o[2] = v.z; o[3] = v.w;
    } else {
        uint2 u = *(const uint2*)((const ushort*)p + e0);
        if (mode == MD_BF16) {
            float2 a = unpack2(u.x), b = unpack2(u.y);
            o[0] = a.x; o[1] = a.y; o[2] = b.x; o[3] = b.y;
        } else {
            o[0] = h2f(u.x & 0xFFFFu); o[1] = h2f(u.x >> 16);
            o[2] = h2f(u.y & 0xFFFFu); o[3] = h2f(u.y >> 16);
        }
    }
}
__device__ __forceinline__ float loadS(const void* p, int mode, size_t i) {
    if (mode == MD_F32) return ((const float*)p)[i];
    unsigned short u = ((const ushort*)p)[i];
    if (mode == MD_BF16) { union { unsigned i; float f; } c; c.i = (unsigned)u << 16; return c.f; }
    return h2f(u);
}

// raw 16-elem A load (bits only, so loads can fly under the MFMA phase)
__device__ __forceinline__ void loadAraw(const void* p, int m, size_t e, uint4* r) {
    if (m == MD_F32) {
        const float* f = (const float*)p + e;
        r[0] = *(const uint4*)(f);
        r[1] = *(const uint4*)(f + 4);
        r[2] = *(const uint4*)(f + 8);
        r[3] = *(const uint4*)(f + 12);
    } else {
        const ushort* s = (const ushort*)p + e;
        r[0] = *(const uint4*)s;
        r[1] = *(const uint4*)(s + 8);
    }
}
__device__ __forceinline__ void cvtA16(const uint4* r, int m, uint4* o2) {
    union { ushort u[16]; uint4 v[2]; } o;
    if (m == MD_F32) {
        const float* f = (const float*)r;
#pragma unroll
        for (int j = 0; j < 16; ++j) o.u[j] = f2bf(f[j]);
    } else if (m == MD_BF16) {
        o.v[0] = r[0]; o.v[1] = r[1];
    } else {
        const ushort* s = (const ushort*)r;
#pragma unroll
        for (int j = 0; j < 16; ++j) o.u[j] = f2bf(h2f(s[j]));
    }
    o2[0] = o.v[0]; o2[1] = o.v[1];
}

// =====================================================================
// Fused dtype sniff: one block per float tensor.
// =====================================================================
struct SniffArgs { const void* p[10]; int nhalf[10]; };

__global__ void sniff_all(SniffArgs a, int* __restrict__ modes) {
    __shared__ int cE, cO;
    const int slots[9] = {0, 1, 2, 4, 5, 6, 7, 8, 9};
    const int slot = slots[blockIdx.x];
    const ushort* p = (const ushort*)a.p[slot];
    const int nhalf = a.nhalf[slot];
    if (threadIdx.x == 0) { cE = 0; cO = 0; }
    __syncthreads();
    int e = 0, o = 0;
    for (int i = threadIdx.x; i < nhalf; i += 256) {
        unsigned ex = (p[i] >> 7) & 0xFFu;
        int hit = (ex < 100u || ex == 0xFFu) ? 1 : 0;
        if (i & 1) o += hit; else e += hit;
    }
    atomicAdd(&cE, e);
    atomicAdd(&cO, o);
    __syncthreads();
    if (threadIdx.x == 0) {
        int total = cE + cO;
        modes[slot] = (total < 48) ? MD_BF16 : ((cO * 4 < cE) ? MD_F32 : MD_F16);
    }
}

// =====================================================================
// Mask bit-pack: mask[B][S][S] int32 -> 1 bit/elem (2 MB, L2-resident).
// =====================================================================
__global__ __launch_bounds__(256) void mpack(
    const int* __restrict__ mask, unsigned int* __restrict__ pm)
{
    const int w = blockIdx.x * 256 + threadIdx.x;
    const int* p = mask + (size_t)w * 32;
    unsigned int bits = 0u;
#pragma unroll
    for (int j = 0; j < 8; ++j) {
        int4 v = *(const int4*)(p + j * 4);
        bits |= (v.x ? 1u : 0u) << (4 * j);
        bits |= (v.y ? 1u : 0u) << (4 * j + 1);
        bits |= (v.z ? 1u : 0u) << (4 * j + 2);
        bits |= (v.w ? 1u : 0u) << (4 * j + 3);
    }
    pm[w] = bits;
}

// =====================================================================
// Weight transpose + bf16 convert: W[k][n] (any dtype) -> Wt[n][k] bf16.
// 64x64 tiles, grid (16,16,ngroup) — z selects the weight tensor.
// =====================================================================
struct WtArgs { const void* W[3]; ushort* Wt[3]; int slot[3]; };

__device__ __forceinline__ void wtrans_body(
    const void* __restrict__ W, ushort* __restrict__ Wt, int m)
{
    __shared__ ushort T[64][68];
    const int tid = threadIdx.x;
    const int k0 = blockIdx.y * 64, n0 = blockIdx.x * 64;

    const int r = tid >> 2, c = (tid & 3) * 16;
    float t[4];
#pragma unroll
    for (int j = 0; j < 4; ++j) {
        load4m(W, m, (size_t)(k0 + r) * DM + n0 + c + 4 * j, t);
#pragma unroll
        for (int i = 0; i < 4; ++i) T[r][c + 4 * j + i] = f2bf(t[i]);
    }
    __syncthreads();

    const int rn = tid >> 2, ck = (tid & 3) * 16;
    union { ushort u[8]; uint4 v; } p0, p1;
#pragma unroll
    for (int j = 0; j < 8; ++j) { p0.u[j] = T[ck + j][rn]; p1.u[j] = T[ck + 8 + j][rn]; }
    ushort* op = &Wt[(size_t)(n0 + rn) * DM + k0 + ck];
    *(uint4*)op = p0.v;
    *(uint4*)(op + 8) = p1.v;
}

__global__ __launch_bounds__(256) void wtrans3(WtArgs a, const int* __restrict__ modes) {
    const int g = blockIdx.z;
    wtrans_body(a.W[g], a.Wt[g], modes[a.slot[g]]);
}
__global__ __launch_bounds__(256) void wtrans(
    const void* __restrict__ W, ushort* __restrict__ Wt,
    const int* __restrict__ modes, int wslot)
{
    wtrans_body(W, Wt, modes[wslot]);
}

// =====================================================================
// Fused QKV projection: z selects {query,key,value} @ {Wtq,Wtk,Wtv}.
// 128x128 tile, BK=32.  A reg-staged with in-kernel dtype convert into
// padded LDS [128][40] (2-way-max conflicts); B via global_load_lds DMA
// into linear [128][32].  Double-buffered, issue-early; __syncthreads
// drains vmcnt+lgkm per step.  1536 blocks -> ~4 blocks/CU.
// =====================================================================
__global__ __launch_bounds__(256, 4) void projqkv(
    const void* __restrict__ Aq, const void* __restrict__ Ak, const void* __restrict__ Av,
    const ushort* __restrict__ Wtq, const ushort* __restrict__ Wtk, const ushort* __restrict__ Wtv,
    ushort* __restrict__ Qo, ushort* __restrict__ Ko, ushort* __restrict__ Vo,
    const int* __restrict__ modes)
{
    __shared__ __align__(16) ushort As[2][128 * 40];
    __shared__ __align__(16) ushort Bs[2][128 * 32];

    const int z = blockIdx.z;
    const void* A = (z == 0) ? Aq : (z == 1) ? Ak : Av;
    const ushort* Wt = (z == 0) ? Wtq : (z == 1) ? Wtk : Wtv;
    ushort* Out = (z == 0) ? Qo : (z == 1) ? Ko : Vo;
    const int vmode = (z == 2);
    const float scale = (z == 0) ? 0.125f : 1.0f;
    const int m = modes[z];

    const int tid = threadIdx.x;
    const int lane = tid & 63, wv = tid >> 6;
    const int quad = lane >> 4, L = lane & 15;
    const int bid = blockIdx.y * gridDim.x + blockIdx.x;   // 512 per z
    const int swz = (bid & 7) * 64 + (bid >> 3);           // XCD-chunked
    const int m0 = (swz >> 3) * 128, n0 = (swz & 7) * 128;
    const int wm = (wv >> 1) * 64, wn = (wv & 1) * 64;

    // B staging (DMA): 8 wave-calls of 1KB fill the 8KB tile
    const int e0 = (wv * 2 + 0) * 512 + lane * 8;
    const int e1 = (wv * 2 + 1) * 512 + lane * 8;
    const ushort* gB0 = Wt + (size_t)(n0 + (e0 >> 5)) * DM + (e0 & 31);
    const ushort* gB1 = Wt + (size_t)(n0 + (e1 >> 5)) * DM + (e1 & 31);

    // A staging (reg): thread owns (row = tid>>1, 16-elem seg = tid&1)
    const int arow = tid >> 1, aseg = tid & 1;
    const size_t aoff = (size_t)(m0 + arow) * DM + aseg * 16;
    const int alds = arow * 40 + aseg * 16;

    f32x4 acc[4][4];
#pragma unroll
    for (int i = 0; i < 4; ++i)
#pragma unroll
        for (int j = 0; j < 4; ++j) { acc[i][j][0] = 0.f; acc[i][j][1] = 0.f; acc[i][j][2] = 0.f; acc[i][j][3] = 0.f; }

    // prologue: stage tile 0 into buf 0
    {
        gl_lds16(gB0, &Bs[0][e0]);
        gl_lds16(gB1, &Bs[0][e1]);
        uint4 ar[4], ao[2];
        loadAraw(A, m, aoff, ar);
        cvtA16(ar, m, ao);
        *(uint4*)&As[0][alds]     = ao[0];
        *(uint4*)&As[0][alds + 8] = ao[1];
    }
    __syncthreads();

    int cur = 0;
    for (int kt = 0; kt < 31; ++kt) {
        const int kn = (kt + 1) * 32;
        const int nxt = cur ^ 1;
        // issue next tile's loads FIRST — they fly across the MFMA phase
        gl_lds16(gB0 + kn, &Bs[nxt][e0]);
        gl_lds16(gB1 + kn, &Bs[nxt][e1]);
        uint4 ar[4], ao[2];
        loadAraw(A, m, aoff + kn, ar);

        bf16x8 af[4], bfr[4];
#pragma unroll
        for (int tm = 0; tm < 4; ++tm) af[tm] = *(const bf16x8*)&As[cur][(wm + tm * 16 + L) * 40 + quad * 8];
#pragma unroll
        for (int tn = 0; tn < 4; ++tn) bfr[tn] = *(const bf16x8*)&Bs[cur][(wn + tn * 16 + L) * 32 + quad * 8];
#pragma unroll
        for (int tm = 0; tm < 4; ++tm)
#pragma unroll
            for (int tn = 0; tn < 4; ++tn)
                acc[tm][tn] = MFMA16(af[tm], bfr[tn], acc[tm][tn]);

        // convert + LDS-write next A (waits only its own loads)
        cvtA16(ar, m, ao);
        *(uint4*)&As[nxt][alds]     = ao[0];
        *(uint4*)&As[nxt][alds + 8] = ao[1];

        __syncthreads();   // drains vmcnt (B DMA) + lgkm (A writes)
        cur ^= 1;
    }
    {   // tail tile
        bf16x8 af[4], bfr[4];
#pragma unroll
        for (int tm = 0; tm < 4; ++tm) af[tm] = *(const bf16x8*)&As[cur][(wm + tm * 16 + L) * 40 + quad * 8];
#pragma unroll
        for (int tn = 0; tn < 4; ++tn) bfr[tn] = *(const bf16x8*)&Bs[cur][(wn + tn * 16 + L) * 32 + quad * 8];
#pragma unroll
        for (int tm = 0; tm < 4; ++tm)
#pragma unroll
            for (int tn = 0; tn < 4; ++tn)
                acc[tm][tn] = MFMA16(af[tm], bfr[tn], acc[tm][tn]);
    }

#pragma unroll
    for (int tm = 0; tm < 4; ++tm)
#pragma unroll
        for (int tn = 0; tn < 4; ++tn)
#pragma unroll
            for (int r = 0; r < 4; ++r) {
                const int mm = m0 + wm + tm * 16 + quad * 4 + r;
                const int n = n0 + wn + tn * 16 + L;
                const int b = mm >> 11, s = mm & 2047;
                const int h = n >> 6, d = n & 63;
                const size_t o = vmode
                    ? ((size_t)(b * HH + h) * DKV + d) * SS + s
                    : ((size_t)(b * HH + h) * SS + s) * DKV + d;
                Out[o] = f2bf(acc[tm][tn][r] * scale);
            }
}

// =====================================================================
// MFMA flash attention, fixed-base softmax (Q pre-scaled by 1/8).
// Packed bitmask (2 MB, L2-resident).  XCD-chunked swizzle: each XCD
// owns 8 complete bh (4MB K/V working set).  setprio around MFMA.
// =====================================================================
__global__ __launch_bounds__(256) void attn_mfma(
    const ushort* __restrict__ Q, const ushort* __restrict__ K,
    const ushort* __restrict__ Vt, const unsigned int* __restrict__ pm,
    ushort* __restrict__ Xo)
{
    __shared__ __align__(16) ushort Ks[64][72];
    __shared__ __align__(16) ushort Vs[64][72];
    __shared__ __align__(16) ushort Ps[64][72];

    const int tid = threadIdx.x;
    const int lane = tid & 63, wv = tid >> 6;
    const int quad = lane >> 4, L = lane & 15;
    const int bid = blockIdx.y * gridDim.x + blockIdx.x;   // 2048, x fastest
    const int swz = (bid & 7) * 256 + (bid >> 3);          // XCD-chunked
    const int bh = swz >> 5, b = bh >> 4, h = bh & 15;
    const int q0 = (swz & 31) * 64;

    const ushort* qp = &Q[((size_t)bh * SS + q0 + wv * 16 + L) * DKV + quad * 8];
    const bf16x8 aq0 = *(const bf16x8*)qp;
    const bf16x8 aq1 = *(const bf16x8*)(qp + 32);

    f32x4 O[4];
    float lacc[4];
#pragma unroll
    for (int t = 0; t < 4; ++t) { O[t][0] = 0.f; O[t][1] = 0.f; O[t][2] = 0.f; O[t][3] = 0.f; }
#pragma unroll
    for (int r = 0; r < 4; ++r) lacc[r] = 0.f;

    const int sr = tid >> 2, sg = tid & 3;
    const ushort* kbase = &K[((size_t)bh * SS + sr) * DKV + sg * 16];
    const ushort* vbase = &Vt[((size_t)bh * DKV + sr) * SS + sg * 16];
    const unsigned int* pmr[4];
#pragma unroll
    for (int r = 0; r < 4; ++r)
        pmr[r] = pm + ((size_t)b * SS + q0 + wv * 16 + quad * 4 + r) * 64;

    for (int kt = 0; kt < 32; ++kt) {
        __syncthreads();
        *(uint4*)&Ks[sr][sg * 16]     = *(const uint4*)kbase;
        *(uint4*)&Ks[sr][sg * 16 + 8] = *(const uint4*)(kbase + 8);
        *(uint4*)&Vs[sr][sg * 16]     = *(const uint4*)vbase;
        *(uint4*)&Vs[sr][sg * 16 + 8] = *(const uint4*)(vbase + 8);
        kbase += 64 * DKV;
        vbase += 64;

        uint2 mw[4];
#pragma unroll
        for (int r = 0; r < 4; ++r) mw[r] = *(const uint2*)(pmr[r] + 2 * kt);

        __syncthreads();

        f32x4 sc[4];
        __builtin_amdgcn_s_setprio(1);
#pragma unroll
        for (int t = 0; t < 4; ++t) {
            bf16x8 b0 = *(const bf16x8*)&Ks[t * 16 + L][quad * 8];
            bf16x8 b1 = *(const bf16x8*)&Ks[t * 16 + L][32 + quad * 8];
            f32x4 c; c[0] = 0.f; c[1] = 0.f; c[2] = 0.f; c[3] = 0.f;
            c = MFMA16(aq0, b0, c);
            c = MFMA16(aq1, b1, c);
            sc[t] = c;
        }
        __builtin_amdgcn_s_setprio(0);

#pragma unroll
        for (int r = 0; r < 4; ++r) {
            const unsigned mx = mw[r].x, my = mw[r].y;
#pragma unroll
            for (int t = 0; t < 4; ++t) {
                const float s = fminf(sc[t][r], 30.f);
                const float e = __expf(s);
                const unsigned wsel = (t & 2) ? my : mx;
                const float p = ((wsel >> ((t & 1) * 16 + L)) & 1u) ? e : 0.f;
                lacc[r] += p;
                Ps[wv * 16 + quad * 4 + r][t * 16 + L] = f2bf_t(p);
            }
        }

        bf16x8 ap0 = *(const bf16x8*)&Ps[wv * 16 + L][quad * 8];
        bf16x8 ap1 = *(const bf16x8*)&Ps[wv * 16 + L][32 + quad * 8];
        __builtin_amdgcn_s_setprio(1);
#pragma unroll
        for (int t = 0; t < 4; ++t) {
            bf16x8 v0 = *(const bf16x8*)&Vs[t * 16 + L][quad * 8];
            bf16x8 v1 = *(const bf16x8*)&Vs[t * 16 + L][32 + quad * 8];
            O[t] = MFMA16(ap0, v0, O[t]);
            O[t] = MFMA16(ap1, v1, O[t]);
        }
        __builtin_amdgcn_s_setprio(0);
    }

    float inv[4];
#pragma unroll
    for (int r = 0; r < 4; ++r) {
        float l = lacc[r];
#pragma unroll
        for (int off = 1; off < 16; off <<= 1) l += __shfl_xor(l, off, 64);
        inv[r] = 1.f / l;
    }
#pragma unroll
    for (int t = 0; t < 4; ++t)
#pragma unroll
        for (int r = 0; r < 4; ++r) {
            const int qg = q0 + wv * 16 + quad * 4 + r;
            Xo[((size_t)b * SS + qg) * DM + h * DKV + t * 16 + L] = f2bf(O[t][r] * inv[r]);
        }
}

// =====================================================================
// MFMA output projection: X(bf16) @ Wt_out + query -> fp32.  dbuf DMA.
// =====================================================================
__global__ __launch_bounds__(256) void oproj_mfma(
    const ushort* __restrict__ Xin, const ushort* __restrict__ Wt,
    const void* __restrict__ Qres, float* __restrict__ Out,
    const int* __restrict__ modes)
{
    __shared__ __align__(16) ushort Asf[2][4096];
    __shared__ __align__(16) ushort Bsf[2][4096];

    const int tid = threadIdx.x;
    const int lane = tid & 63, wv = tid >> 6;
    const int quad = lane >> 4, L = lane & 15;
    const int bid = blockIdx.y * gridDim.x + blockIdx.x;
    const int swz = (bid & 7) * 64 + (bid >> 3);
    const int m0 = (swz >> 3) * 128, n0 = (swz & 7) * 128;
    const int wm = (wv >> 1) * 64, wn = (wv & 1) * 64;
    const int mq = modes[0];

    const int e0 = (wv * 2 + 0) * 512 + lane * 8;
    const int e1 = (wv * 2 + 1) * 512 + lane * 8;
    const ushort* gA0 = Xin + (size_t)(m0 + (e0 >> 5)) * DM + (e0 & 31);
    const ushort* gA1 = Xin + (size_t)(m0 + (e1 >> 5)) * DM + (e1 & 31);
    const ushort* gB0 = Wt  + (size_t)(n0 + (e0 >> 5)) * DM + (e0 & 31);
    const ushort* gB1 = Wt  + (size_t)(n0 + (e1 >> 5)) * DM + (e1 & 31);

    f32x4 acc[4][4];
#pragma unroll
    for (int i = 0; i < 4; ++i)
#pragma unroll
        for (int j = 0; j < 4; ++j) { acc[i][j][0] = 0.f; acc[i][j][1] = 0.f; acc[i][j][2] = 0.f; acc[i][j][3] = 0.f; }

    gl_lds16(gA0, &Asf[0][e0]);
    gl_lds16(gA1, &Asf[0][e1]);
    gl_lds16(gB0, &Bsf[0][e0]);
    gl_lds16(gB1, &Bsf[0][e1]);
    wait_vm0_barrier();

    int cur = 0;
    for (int kt = 0; kt < 31; ++kt) {
        const int kn = (kt + 1) * 32;
        gl_lds16(gA0 + kn, &Asf[cur ^ 1][e0]);
        gl_lds16(gA1 + kn, &Asf[cur ^ 1][e1]);
        gl_lds16(gB0 + kn, &Bsf[cur ^ 1][e0]);
        gl_lds16(gB1 + kn, &Bsf[cur ^ 1][e1]);

        bf16x8 af[4], bfr[4];
#pragma unroll
        for (int tm = 0; tm < 4; ++tm) af[tm] = *(const bf16x8*)&Asf[cur][(wm + tm * 16 + L) * 32 + quad * 8];
#pragma unroll
        for (int tn = 0; tn < 4; ++tn) bfr[tn] = *(const bf16x8*)&Bsf[cur][(wn + tn * 16 + L) * 32 + quad * 8];
#pragma unroll
        for (int tm = 0; tm < 4; ++tm)
#pragma unroll
            for (int tn = 0; tn < 4; ++tn)
                acc[tm][tn] = MFMA16(af[tm], bfr[tn], acc[tm][tn]);

        wait_vm0_barrier();
        cur ^= 1;
    }
    {
        bf16x8 af[4], bfr[4];
#pragma unroll
        for (int tm = 0; tm < 4; ++tm) af[tm] = *(const bf16x8*)&Asf[cur][(wm + tm * 16 + L) * 32 + quad * 8];
#pragma unroll
        for (int tn = 0; tn < 4; ++tn) bfr[tn] = *(const bf16x8*)&Bsf[cur][(wn + tn * 16 + L) * 32 + quad * 8];
#pragma unroll
        for (int tm = 0; tm < 4; ++tm)
#pragma unroll
            for (int tn = 0; tn < 4; ++tn)
                acc[tm][tn] = MFMA16(af[tm], bfr[tn], acc[tm][tn]);
    }

#pragma unroll
    for (int tm = 0; tm < 4; ++tm)
#pragma unroll
        for (int tn = 0; tn < 4; ++tn)
#pragma unroll
            for (int r = 0; r < 4; ++r) {
                const int mm = m0 + wm + tm * 16 + quad * 4 + r;
                const int n = n0 + wn + tn * 16 + L;
                const size_t idx = (size_t)mm * DM + n;
                Out[idx] = acc[tm][tn][r] + loadS(Qres, mq, idx);
            }
}

// =====================================================================
// In-place LayerNorm over d_out rows (8192 x 1024 fp32), 1 row per wave.
// =====================================================================
__global__ __launch_bounds__(256) void ln_k(
    float* __restrict__ Out, const void* __restrict__ G,
    const void* __restrict__ Bt, const int* __restrict__ modes)
{
    const int tid = threadIdx.x, wv = tid >> 6, lane = tid & 63;
    const int row = blockIdx.x * 4 + wv;
    const int mg = modes[8], mb = modes[9];
    const size_t base = (size_t)row * DM + lane * 16;

    float v[16];
    float s = 0.f, q = 0.f;
#pragma unroll
    for (int j = 0; j < 16; j += 4) {
        float4 t = *(const float4*)&Out[base + j];
        v[j] = t.x; v[j+1] = t.y; v[j+2] = t.z; v[j+3] = t.w;
        s += t.x + t.y + t.z + t.w;
        q += t.x*t.x + t.y*t.y + t.z*t.z + t.w*t.w;
    }
#pragma unroll
    for (int off = 1; off < 64; off <<= 1) {
        s += __shfl_xor(s, off, 64);
        q += __shfl_xor(q, off, 64);
    }
    const float mu = s * (1.f / 1024.f);
    const float var = q * (1.f / 1024.f) - mu * mu;
    const float inv = rsqrtf(var + LNEPS);

    float gj[16], bj[16];
#pragma unroll
    for (int j = 0; j < 16; j += 4) {
        load4m(G,  mg, (size_t)lane * 16 + j, gj + j);
        load4m(Bt, mb, (size_t)lane * 16 + j, bj + j);
    }
#pragma unroll
    for (int j = 0; j < 16; j += 4) {
        float4 o;
        o.x = (v[j]   - mu) * inv * gj[j]   + bj[j];
        o.y = (v[j+1] - mu) * inv * gj[j+1] + bj[j+1];
        o.z = (v[j+2] - mu) * inv * gj[j+2] + bj[j+2];
        o.w = (v[j+3] - mu) * inv * gj[j+3] + bj[j+3];
        *(float4*)&Out[base + j] = o;
    }
}

// =====================================================================
extern "C" void kernel_launch(void* const* d_in, const int* in_sizes, int n_in,
                              void* d_out, int out_size, void* d_ws, size_t ws_size,
                              hipStream_t stream)
{
    const void* query = d_in[0];
    const void* key_i = d_in[1];
    const void* value = d_in[2];
    const int*  mask  = (const int*)d_in[3];
    const void* w_qs  = d_in[4];
    const void* w_ks  = d_in[5];
    const void* w_vs  = d_in[6];
    const void* w_out = d_in[7];
    const void* ln_g  = d_in[8];
    const void* ln_b  = d_in[9];
    float* out = (float*)d_out;

    // ws layout: [modes 256B][Qw 16MB][Kw 16MB][Vw 16MB][Xw 16MB]
    // d_out (32MB, dead until oproj): pmask@0 (2MB), Wtq/Wtk/Wtv @4/8/12MB.
    // Wt2 (w_out transpose) aliases dead-after-attn Qw — must NOT be in
    // d_out (oproj epilogue would race with its own Wt reads).
    int* modes = (int*)d_ws;
    const size_t PE = (size_t)BB * HH * SS * DKV;  // 8,388,608
    ushort* Qw = (ushort*)((char*)d_ws + 256);
    ushort* Kw = Qw + PE;
    ushort* Vw = Kw + PE;   // transposed layout [bh][d][s]
    ushort* Xw = Vw + PE;
    ushort* Wtq  = (ushort*)((char*)d_out + (4  << 20));
    ushort* Wtk  = (ushort*)((char*)d_out + (8  << 20));
    ushort* Wtv  = (ushort*)((char*)d_out + (12 << 20));
    ushort* Wt2  = Qw;                                    // 2MB, post-attn
    unsigned int* pmask = (unsigned int*)d_out;           // 2MB packed mask

    SniffArgs sa;
    for (int i = 0; i < 10; ++i) {
        sa.p[i] = d_in[i];
        sa.nhalf[i] = in_sizes[i] < 4096 ? in_sizes[i] : 4096;
    }
    sniff_all<<<9, 256, 0, stream>>>(sa, modes);
    mpack<<<2048, 256, 0, stream>>>(mask, pmask);

    WtArgs wa;
    wa.W[0] = w_qs; wa.Wt[0] = Wtq; wa.slot[0] = 4;
    wa.W[1] = w_ks; wa.Wt[1] = Wtk; wa.slot[1] = 5;
    wa.W[2] = w_vs; wa.Wt[2] = Wtv; wa.slot[2] = 6;
    wtrans3<<<dim3(16, 16, 3), 256, 0, stream>>>(wa, modes);

    projqkv<<<dim3(8, 64, 3), 256, 0, stream>>>(
        query, key_i, value, Wtq, Wtk, Wtv, Qw, Kw, Vw, modes);

    attn_mfma<<<dim3(32, 64), 256, 0, stream>>>(Qw, Kw, Vw, pmask, Xw);

    wtrans<<<dim3(16, 16), 256, 0, stream>>>(w_out, Wt2, modes, 7);
    oproj_mfma<<<dim3(8, 64), 256, 0, stream>>>(Xw, Wt2, query, out, modes);
    ln_k<<<2048, 256, 0, stream>>>(out, ln_g, ln_b, modes);
}